// Round 4
// baseline (389.371 us; speedup 1.0000x reference)
//
#include <hip/hip_runtime.h>
#include <math.h>

// x: [B=8, C=1, D=3, H=1536, W=1536] fp32
// out = (x - maxpool3x3x3(x) + 1e-5 > 0) ? x : 0 (pool broadcast over depth).
// Separable: m = depth-max over 3 planes, mp = 3x3 spatial max of m.
//
// MLP-first structure: each wave owns 8 output rows x 256 cols. It issues ALL
// 30 strip loads (10 rows x 3 planes, 1 KB each) + 3 edge loads back-to-back
// into register arrays (~31 KB in flight per wave), THEN computes. This is
// the fix for the 143-us plateau: prior kernels had ~3 KB/wave in flight
// (compiler sank loads; VGPR_Count=40) -> latency-bound at 3.4 TB/s.

#define Hh   1536
#define Ww   1536
#define EPSf 1e-5f
#define RPW  8                    // output rows per wave
#define NR   (RPW + 2)            // loaded rows per wave = 10
#define BPR  (4 * RPW)            // rows per block (4 waves) = 32
#define NBANDS 6                  // 256-col bands (64 lanes x float4)
#define NSTRIP (Hh / BPR)         // 48
#define PER_XCD (NSTRIP * NBANDS) // 288 blocks per batch; one batch per XCD

typedef float f4 __attribute__((ext_vector_type(4)));

__global__ __launch_bounds__(256, 2) void nms3d_kernel(const float* __restrict__ x,
                                                       float* __restrict__ out) {
    const int tid  = threadIdx.x;
    const int lane = tid & 63;
    const int wv   = tid >> 6;

    // XCD-aware mapping: one batch per XCD, staggered strip order.
    const int xcd = blockIdx.x & 7;
    int j = blockIdx.x >> 3;
    j = (j + xcd * 37) % PER_XCD;
    const int band = j % NBANDS;
    const int s    = j / NBANDS;
    const int b    = xcd;

    const int w0 = band * 256;
    const int h0 = s * BPR + wv * RPW;
    const int wc = w0 + lane * 4;

    const size_t plane = (size_t)Hh * Ww;
    const float* xb = x + (size_t)b * 3 * plane;
    float*       ob = out + (size_t)b * 3 * plane;

    const float NI = -INFINITY;
    const float PIF = INFINITY;

    // ---------------- bulk load phase: 30 + 3 independent loads ----------------
    f4 a0[NR], a1[NR], a2[NR];
#pragma unroll
    for (int r = 0; r < NR; ++r) {
        const int h  = h0 - 1 + r;
        const int hc = h < 0 ? 0 : (h > Hh - 1 ? Hh - 1 : h);   // clamped addr
        const float* p = xb + (size_t)hc * Ww + wc;
        a0[r] = *(const f4*)(p);
        a1[r] = *(const f4*)(p + plane);
        a2[r] = *(const f4*)(p + 2 * plane);
    }
    // edge columns, lane-distributed: left (w0-1) rows in lanes 0..9,
    // right (w0+256) rows in lanes 32..41; clamped unconditional loads.
    const int er  = lane & 31;
    const int ecn = (lane < 32) ? (w0 - 1) : (w0 + 256);
    const int ecc = ecn < 0 ? 0 : (ecn > Ww - 1 ? Ww - 1 : ecn);
    const int eh  = h0 - 1 + er;
    const int ehc = eh < 0 ? 0 : (eh > Hh - 1 ? Hh - 1 : eh);
    const float* q = xb + (size_t)ehc * Ww + ecc;
    const float q0 = q[0];
    const float q1 = q[plane];
    const float q2 = q[2 * plane];

    // ---------------- compute phase: depth-max rows ----------------
    f4 m[NR];
#pragma unroll
    for (int r = 0; r < NR; ++r) {
        const int h = h0 - 1 + r;
        const float bound = ((unsigned)h < (unsigned)Hh) ? PIF : NI;
        m[r].x = fminf(fmaxf(a0[r].x, fmaxf(a1[r].x, a2[r].x)), bound);
        m[r].y = fminf(fmaxf(a0[r].y, fmaxf(a1[r].y, a2[r].y)), bound);
        m[r].z = fminf(fmaxf(a0[r].z, fmaxf(a1[r].z, a2[r].z)), bound);
        m[r].w = fminf(fmaxf(a0[r].w, fmaxf(a1[r].w, a2[r].w)), bound);
    }
    const bool eok = (er < NR) && ((unsigned)ecn < (unsigned)Ww) &&
                     ((unsigned)eh < (unsigned)Hh);
    const float eV = eok ? fmaxf(q0, fmaxf(q1, q2)) : NI;

    // ---------------- pool + mask + store ----------------
#pragma unroll
    for (int i = 0; i < RPW; ++i) {
        f4 vm;
        vm.x = fmaxf(m[i].x, fmaxf(m[i + 1].x, m[i + 2].x));
        vm.y = fmaxf(m[i].y, fmaxf(m[i + 1].y, m[i + 2].y));
        vm.z = fmaxf(m[i].z, fmaxf(m[i + 1].z, m[i + 2].z));
        vm.w = fmaxf(m[i].w, fmaxf(m[i + 1].w, m[i + 2].w));

        const float fl = __shfl_up(vm.w, 1);
        const float fr = __shfl_down(vm.x, 1);
        const float eL = fmaxf(fmaxf(__shfl(eV, i), __shfl(eV, i + 1)),
                               __shfl(eV, i + 2));
        const float eR = fmaxf(fmaxf(__shfl(eV, 32 + i), __shfl(eV, 33 + i)),
                               __shfl(eV, 34 + i));
        const float left  = (lane == 0)  ? eL : fl;
        const float right = (lane == 63) ? eR : fr;

        f4 mp;
        mp.x = fmaxf(left, fmaxf(vm.x, vm.y));
        mp.y = fmaxf(vm.x, fmaxf(vm.y, vm.z));
        mp.z = fmaxf(vm.y, fmaxf(vm.z, vm.w));
        mp.w = fmaxf(vm.z, fmaxf(vm.w, right));

        const int rc = i + 1;   // center row index in arrays
        float* po = ob + (size_t)(h0 + i) * Ww + wc;
        f4 o;
        o.x = ((a0[rc].x - mp.x) + EPSf > 0.0f) ? a0[rc].x : 0.0f;
        o.y = ((a0[rc].y - mp.y) + EPSf > 0.0f) ? a0[rc].y : 0.0f;
        o.z = ((a0[rc].z - mp.z) + EPSf > 0.0f) ? a0[rc].z : 0.0f;
        o.w = ((a0[rc].w - mp.w) + EPSf > 0.0f) ? a0[rc].w : 0.0f;
        __builtin_nontemporal_store(o, (f4*)po);
        o.x = ((a1[rc].x - mp.x) + EPSf > 0.0f) ? a1[rc].x : 0.0f;
        o.y = ((a1[rc].y - mp.y) + EPSf > 0.0f) ? a1[rc].y : 0.0f;
        o.z = ((a1[rc].z - mp.z) + EPSf > 0.0f) ? a1[rc].z : 0.0f;
        o.w = ((a1[rc].w - mp.w) + EPSf > 0.0f) ? a1[rc].w : 0.0f;
        __builtin_nontemporal_store(o, (f4*)(po + plane));
        o.x = ((a2[rc].x - mp.x) + EPSf > 0.0f) ? a2[rc].x : 0.0f;
        o.y = ((a2[rc].y - mp.y) + EPSf > 0.0f) ? a2[rc].y : 0.0f;
        o.z = ((a2[rc].z - mp.z) + EPSf > 0.0f) ? a2[rc].z : 0.0f;
        o.w = ((a2[rc].w - mp.w) + EPSf > 0.0f) ? a2[rc].w : 0.0f;
        __builtin_nontemporal_store(o, (f4*)(po + 2 * plane));
    }
}

extern "C" void kernel_launch(void* const* d_in, const int* in_sizes, int n_in,
                              void* d_out, int out_size, void* d_ws, size_t ws_size,
                              hipStream_t stream) {
    const float* x = (const float*)d_in[0];
    float* out = (float*)d_out;
    const int grid = 8 * NSTRIP * NBANDS;   // 2304 blocks
    nms3d_kernel<<<dim3(grid), dim3(256), 0, stream>>>(x, out);
}

// Round 5
// 386.164 us; speedup vs baseline: 1.0083x; 1.0083x over previous
//
#include <hip/hip_runtime.h>
#include <math.h>

// x: [B=8, C=1, D=3, H=1536, W=1536] fp32
// out = (x - maxpool3x3x3(x) + 1e-5 > 0) ? x : 0 (pool broadcast over depth).
// Separable: m = depth-max over 3 planes, mp = 3x3 spatial max of m.
//
// R5: R4's bulk-load structure + __builtin_amdgcn_sched_barrier(0) fence
// between the load phase and compute phase. R3/R4 showed the machine
// scheduler sinks loads next to uses (VGPR=44, ~3 KB/wave in flight ->
// latency-bound 143 us plateau). The sched_barrier forbids any code motion
// across it, forcing all 33 loads (~33 KB/wave) to be outstanding at once.

#define Hh   1536
#define Ww   1536
#define EPSf 1e-5f
#define RPW  8                    // output rows per wave
#define NR   (RPW + 2)            // loaded rows per wave = 10
#define BPR  (4 * RPW)            // rows per block (4 waves) = 32
#define NBANDS 6                  // 256-col bands (64 lanes x float4)
#define NSTRIP (Hh / BPR)         // 48
#define PER_XCD (NSTRIP * NBANDS) // 288 blocks per batch; one batch per XCD

typedef float f4 __attribute__((ext_vector_type(4)));

__global__ __launch_bounds__(256, 2) void nms3d_kernel(const float* __restrict__ x,
                                                       float* __restrict__ out) {
    const int tid  = threadIdx.x;
    const int lane = tid & 63;
    const int wv   = tid >> 6;

    // XCD-aware mapping: one batch per XCD, staggered strip order.
    const int xcd = blockIdx.x & 7;
    int j = blockIdx.x >> 3;
    j = (j + xcd * 37) % PER_XCD;
    const int band = j % NBANDS;
    const int s    = j / NBANDS;
    const int b    = xcd;

    const int w0 = band * 256;
    const int h0 = s * BPR + wv * RPW;
    const int wc = w0 + lane * 4;

    const size_t plane = (size_t)Hh * Ww;
    const float* xb = x + (size_t)b * 3 * plane;
    float*       ob = out + (size_t)b * 3 * plane;

    const float NI = -INFINITY;
    const float PIF = INFINITY;

    // ---------------- bulk load phase: 30 + 3 independent loads ----------------
    f4 a0[NR], a1[NR], a2[NR];
#pragma unroll
    for (int r = 0; r < NR; ++r) {
        const int h  = h0 - 1 + r;
        const int hc = h < 0 ? 0 : (h > Hh - 1 ? Hh - 1 : h);   // clamped addr
        const float* p = xb + (size_t)hc * Ww + wc;
        a0[r] = *(const f4*)(p);
        a1[r] = *(const f4*)(p + plane);
        a2[r] = *(const f4*)(p + 2 * plane);
    }
    // edge columns, lane-distributed: left (w0-1) rows in lanes 0..9,
    // right (w0+256) rows in lanes 32..41; clamped unconditional loads.
    const int er  = lane & 31;
    const int ecn = (lane < 32) ? (w0 - 1) : (w0 + 256);
    const int ecc = ecn < 0 ? 0 : (ecn > Ww - 1 ? Ww - 1 : ecn);
    const int eh  = h0 - 1 + er;
    const int ehc = eh < 0 ? 0 : (eh > Hh - 1 ? Hh - 1 : eh);
    const float* q = xb + (size_t)ehc * Ww + ecc;
    const float q0 = q[0];
    const float q1 = q[plane];
    const float q2 = q[2 * plane];

    // ---- FENCE: nothing crosses. All loads above stay issued before any
    // compute below; the scheduler cannot sink them to shorten live ranges.
    __builtin_amdgcn_sched_barrier(0);

    // ---------------- compute phase: depth-max rows ----------------
    f4 m[NR];
#pragma unroll
    for (int r = 0; r < NR; ++r) {
        const int h = h0 - 1 + r;
        const float bound = ((unsigned)h < (unsigned)Hh) ? PIF : NI;
        m[r].x = fminf(fmaxf(a0[r].x, fmaxf(a1[r].x, a2[r].x)), bound);
        m[r].y = fminf(fmaxf(a0[r].y, fmaxf(a1[r].y, a2[r].y)), bound);
        m[r].z = fminf(fmaxf(a0[r].z, fmaxf(a1[r].z, a2[r].z)), bound);
        m[r].w = fminf(fmaxf(a0[r].w, fmaxf(a1[r].w, a2[r].w)), bound);
    }
    const bool eok = (er < NR) && ((unsigned)ecn < (unsigned)Ww) &&
                     ((unsigned)eh < (unsigned)Hh);
    const float eV = eok ? fmaxf(q0, fmaxf(q1, q2)) : NI;

    // ---------------- pool + mask + store ----------------
#pragma unroll
    for (int i = 0; i < RPW; ++i) {
        f4 vm;
        vm.x = fmaxf(m[i].x, fmaxf(m[i + 1].x, m[i + 2].x));
        vm.y = fmaxf(m[i].y, fmaxf(m[i + 1].y, m[i + 2].y));
        vm.z = fmaxf(m[i].z, fmaxf(m[i + 1].z, m[i + 2].z));
        vm.w = fmaxf(m[i].w, fmaxf(m[i + 1].w, m[i + 2].w));

        const float fl = __shfl_up(vm.w, 1);
        const float fr = __shfl_down(vm.x, 1);
        const float eL = fmaxf(fmaxf(__shfl(eV, i), __shfl(eV, i + 1)),
                               __shfl(eV, i + 2));
        const float eR = fmaxf(fmaxf(__shfl(eV, 32 + i), __shfl(eV, 33 + i)),
                               __shfl(eV, 34 + i));
        const float left  = (lane == 0)  ? eL : fl;
        const float right = (lane == 63) ? eR : fr;

        f4 mp;
        mp.x = fmaxf(left, fmaxf(vm.x, vm.y));
        mp.y = fmaxf(vm.x, fmaxf(vm.y, vm.z));
        mp.z = fmaxf(vm.y, fmaxf(vm.z, vm.w));
        mp.w = fmaxf(vm.z, fmaxf(vm.w, right));

        const int rc = i + 1;   // center row index in arrays
        float* po = ob + (size_t)(h0 + i) * Ww + wc;
        f4 o;
        o.x = ((a0[rc].x - mp.x) + EPSf > 0.0f) ? a0[rc].x : 0.0f;
        o.y = ((a0[rc].y - mp.y) + EPSf > 0.0f) ? a0[rc].y : 0.0f;
        o.z = ((a0[rc].z - mp.z) + EPSf > 0.0f) ? a0[rc].z : 0.0f;
        o.w = ((a0[rc].w - mp.w) + EPSf > 0.0f) ? a0[rc].w : 0.0f;
        __builtin_nontemporal_store(o, (f4*)po);
        o.x = ((a1[rc].x - mp.x) + EPSf > 0.0f) ? a1[rc].x : 0.0f;
        o.y = ((a1[rc].y - mp.y) + EPSf > 0.0f) ? a1[rc].y : 0.0f;
        o.z = ((a1[rc].z - mp.z) + EPSf > 0.0f) ? a1[rc].z : 0.0f;
        o.w = ((a1[rc].w - mp.w) + EPSf > 0.0f) ? a1[rc].w : 0.0f;
        __builtin_nontemporal_store(o, (f4*)(po + plane));
        o.x = ((a2[rc].x - mp.x) + EPSf > 0.0f) ? a2[rc].x : 0.0f;
        o.y = ((a2[rc].y - mp.y) + EPSf > 0.0f) ? a2[rc].y : 0.0f;
        o.z = ((a2[rc].z - mp.z) + EPSf > 0.0f) ? a2[rc].z : 0.0f;
        o.w = ((a2[rc].w - mp.w) + EPSf > 0.0f) ? a2[rc].w : 0.0f;
        __builtin_nontemporal_store(o, (f4*)(po + 2 * plane));
    }
}

extern "C" void kernel_launch(void* const* d_in, const int* in_sizes, int n_in,
                              void* d_out, int out_size, void* d_ws, size_t ws_size,
                              hipStream_t stream) {
    const float* x = (const float*)d_in[0];
    float* out = (float*)d_out;
    const int grid = 8 * NSTRIP * NBANDS;   // 2304 blocks
    nms3d_kernel<<<dim3(grid), dim3(256), 0, stream>>>(x, out);
}

// Round 6
// 381.414 us; speedup vs baseline: 1.0209x; 1.0125x over previous
//
#include <hip/hip_runtime.h>
#include <math.h>

// x: [B=8, C=1, D=3, H=1536, W=1536] fp32
// out = (x - maxpool3x3x3(x) + 1e-5 > 0) ? x : 0 (pool broadcast over depth).
// Separable: m = depth-max over planes (LDS), mp = 3x3 spatial max of m.
//
// R6 theory: all prior kernels (141+-3 us) read/wrote 1-3 KB bursts with 6 KB
// hops (W-banding) -> DRAM row-activate per burst. This kernel uses FULL-WIDTH
// tiles: each block streams whole 1536-col rows, so every plane access is a
// long sequential run in 4 KB block-wide steps (memcpy-shaped). Loads batched
// 12-deep per thread with a sched fence whose consumers are LDS *stores*
// (un-hoistable, unlike R5's arithmetic consumers).

#define Hh   1536
#define Ww   1536
#define EPSf 1e-5f
#define TH   6                  // output rows per block
#define NRr  (TH + 2)           // LDS rows (with vertical halo) = 8
#define F4W  (Ww / 4)           // 384 f4 per full row
#define ROWP 1544               // [0..2] dead, [3]=left pad, [4..1539]=cols, [1540]=right pad
#define NSTRIP (Hh / TH)        // 256 strips

typedef float f4 __attribute__((ext_vector_type(4)));

__global__ __launch_bounds__(256, 3) void nms3d_kernel(const float* __restrict__ x,
                                                       float* __restrict__ out) {
    __shared__ float sm[NRr][ROWP];     // depth-max rows h0-1 .. h0+TH, 49.4 KB

    const int t = threadIdx.x;
    const int s = blockIdx.x & 255;     // strip (consecutive blocks = adjacent strips)
    const int b = blockIdx.x >> 8;      // batch

    const int h0 = s * TH;
    const size_t plane = (size_t)Hh * Ww;
    const float* xb = x + (size_t)b * 3 * plane;
    float*       ob = out + (size_t)b * 3 * plane;

    const float NI = -INFINITY, PIF = INFINITY;

    // image-edge pads (cols -1 and W) = -inf, once
    if (t < 2 * NRr) {
        const int r = t >> 1;
        sm[r][(t & 1) ? 1540 : 3] = NI;
    }

    // ---------------- Phase 1: depth-max -> LDS, sequential 4 KB bursts ------
    // 8 rows x 384 f4 = 3072 tasks = 12/thread, in 3 groups of 4.
#pragma unroll
    for (int g = 0; g < 3; ++g) {
        f4 v0[4], v1[4], v2[4];
        int rr[4], cc[4];
#pragma unroll
        for (int u = 0; u < 4; ++u) {
            const int tau = t + 256 * (g * 4 + u);
            const int r = tau / F4W;
            const int c = tau - r * F4W;
            rr[u] = r; cc[u] = c;
            const int h  = h0 - 1 + r;
            const int hc = h < 0 ? 0 : (h > Hh - 1 ? Hh - 1 : h);
            const float* p = xb + (size_t)hc * Ww + 4 * c;
            v0[u] = *(const f4*)(p);
            v1[u] = *(const f4*)(p + plane);
            v2[u] = *(const f4*)(p + 2 * plane);
        }
        // Fence: 12 loads stay issued before their consumers. Consumers are
        // LDS stores (data-dep on loads) -> cannot be IR-hoisted above them.
        __builtin_amdgcn_sched_barrier(0);
#pragma unroll
        for (int u = 0; u < 4; ++u) {
            const int h = h0 - 1 + rr[u];
            const float bound = ((unsigned)h < (unsigned)Hh) ? PIF : NI;
            f4 m;
            m.x = fminf(fmaxf(v0[u].x, fmaxf(v1[u].x, v2[u].x)), bound);
            m.y = fminf(fmaxf(v0[u].y, fmaxf(v1[u].y, v2[u].y)), bound);
            m.z = fminf(fmaxf(v0[u].z, fmaxf(v1[u].z, v2[u].z)), bound);
            m.w = fminf(fmaxf(v0[u].w, fmaxf(v1[u].w, v2[u].w)), bound);
            *(f4*)&sm[rr[u]][4 + 4 * cc[u]] = m;
        }
    }
    __syncthreads();

    // ---------------- Phase 2: pool + mask + NT store, sequential bursts -----
    // 6 rows x 384 f4 = 2304 tasks = 9/thread, in 3 groups of 3.
    // x re-read is L2/L3-hot (phase 1 touched it microseconds ago).
#pragma unroll
    for (int g = 0; g < 3; ++g) {
        f4 a0[3], a1[3], a2[3];
        int rr[3], cc[3];
#pragma unroll
        for (int u = 0; u < 3; ++u) {
            const int tau = t + 256 * (g * 3 + u);
            const int r = tau / F4W;
            const int c = tau - r * F4W;
            rr[u] = r; cc[u] = c;
            const float* p = xb + (size_t)(h0 + r) * Ww + 4 * c;
            a0[u] = *(const f4*)(p);
            a1[u] = *(const f4*)(p + plane);
            a2[u] = *(const f4*)(p + 2 * plane);
        }
        __builtin_amdgcn_sched_barrier(0);
#pragma unroll
        for (int u = 0; u < 3; ++u) {
            const int r = rr[u], c = cc[u];
            // window cols 4c-1 .. 4c+4 over sm rows r..r+2, via aligned f4s
            float l = NI, w0v = NI, w1v = NI, w2v = NI, w3v = NI, rt = NI;
#pragma unroll
            for (int dr = 0; dr < 3; ++dr) {
                const float* row = &sm[r + dr][0];
                const f4 q0 = *(const f4*)&row[4 * c];       // .w = col 4c-1
                const f4 q1 = *(const f4*)&row[4 * c + 4];   // cols 4c..4c+3
                const f4 q2 = *(const f4*)&row[4 * c + 8];   // .x = col 4c+4
                l   = fmaxf(l,   q0.w);
                w0v = fmaxf(w0v, q1.x);
                w1v = fmaxf(w1v, q1.y);
                w2v = fmaxf(w2v, q1.z);
                w3v = fmaxf(w3v, q1.w);
                rt  = fmaxf(rt,  q2.x);
            }
            f4 mp;
            mp.x = fmaxf(l,   fmaxf(w0v, w1v));
            mp.y = fmaxf(w0v, fmaxf(w1v, w2v));
            mp.z = fmaxf(w1v, fmaxf(w2v, w3v));
            mp.w = fmaxf(w2v, fmaxf(w3v, rt));

            float* po = ob + (size_t)(h0 + r) * Ww + 4 * c;
            f4 o;
            o.x = ((a0[u].x - mp.x) + EPSf > 0.0f) ? a0[u].x : 0.0f;
            o.y = ((a0[u].y - mp.y) + EPSf > 0.0f) ? a0[u].y : 0.0f;
            o.z = ((a0[u].z - mp.z) + EPSf > 0.0f) ? a0[u].z : 0.0f;
            o.w = ((a0[u].w - mp.w) + EPSf > 0.0f) ? a0[u].w : 0.0f;
            __builtin_nontemporal_store(o, (f4*)po);
            o.x = ((a1[u].x - mp.x) + EPSf > 0.0f) ? a1[u].x : 0.0f;
            o.y = ((a1[u].y - mp.y) + EPSf > 0.0f) ? a1[u].y : 0.0f;
            o.z = ((a1[u].z - mp.z) + EPSf > 0.0f) ? a1[u].z : 0.0f;
            o.w = ((a1[u].w - mp.w) + EPSf > 0.0f) ? a1[u].w : 0.0f;
            __builtin_nontemporal_store(o, (f4*)(po + plane));
            o.x = ((a2[u].x - mp.x) + EPSf > 0.0f) ? a2[u].x : 0.0f;
            o.y = ((a2[u].y - mp.y) + EPSf > 0.0f) ? a2[u].y : 0.0f;
            o.z = ((a2[u].z - mp.z) + EPSf > 0.0f) ? a2[u].z : 0.0f;
            o.w = ((a2[u].w - mp.w) + EPSf > 0.0f) ? a2[u].w : 0.0f;
            __builtin_nontemporal_store(o, (f4*)(po + 2 * plane));
        }
    }
}

extern "C" void kernel_launch(void* const* d_in, const int* in_sizes, int n_in,
                              void* d_out, int out_size, void* d_ws, size_t ws_size,
                              hipStream_t stream) {
    const float* x = (const float*)d_in[0];
    float* out = (float*)d_out;
    const int grid = 8 * NSTRIP;   // 2048 blocks, natural (batch-major) order
    nms3d_kernel<<<dim3(grid), dim3(256), 0, stream>>>(x, out);
}